// Round 1
// baseline (161.423 us; speedup 1.0000x reference)
//
#include <hip/hip_runtime.h>
#include <hip/hip_bf16.h>
#include <cstdint>
#include <cstddef>

#define CIN   512
#define COUT  512
#define LLEN  2048
#define BATCH 8
#define KTAP  8
#define LPAD  (LLEN + 8)   // 8 zero halo rows at the front of each batch

typedef __bf16 bf16x8_t __attribute__((ext_vector_type(8)));
typedef float  f32x4_t  __attribute__((ext_vector_type(4)));

__device__ __forceinline__ unsigned short f2bf(float f) {
  __bf16 h = (__bf16)f;                       // RNE fptrunc
  return __builtin_bit_cast(unsigned short, h);
}

__device__ __forceinline__ void gl2lds16(unsigned short* lds, const unsigned short* g) {
  __builtin_amdgcn_global_load_lds(
      (const __attribute__((address_space(1))) unsigned int*)g,
      (__attribute__((address_space(3))) unsigned int*)lds,
      16, 0, 0);
}

// ---------------- pre-pass kernels ----------------

// zero the 8 halo rows (8*CIN bf16) at the start of each batch slab of xtp
__global__ void zero_pad_kernel(unsigned short* __restrict__ xtp) {
  unsigned short* p = xtp + (size_t)blockIdx.x * LPAD * CIN;
  for (int i = threadIdx.x; i < 8 * CIN; i += 256) p[i] = 0;
}

// W (COUT*K, CIN) fp32 -> bf16, same layout
__global__ void convert_w_kernel(const float4* __restrict__ W, ushort4* __restrict__ Wb) {
  int idx = blockIdx.x * 256 + threadIdx.x;   // grid sized exactly: n/4 threads
  float4 v = W[idx];
  ushort4 o;
  o.x = f2bf(v.x); o.y = f2bf(v.y); o.z = f2bf(v.z); o.w = f2bf(v.w);
  Wb[idx] = o;
}

// x (B, CIN, L) fp32 -> xtp (B, 8+L, CIN) bf16 (transpose + cast), rows 8.. hold l=row-8
__global__ void transpose_x_kernel(const float* __restrict__ x, unsigned short* __restrict__ xtp) {
  __shared__ float tile[32][33];
  const int b  = blockIdx.z;
  const int c0 = blockIdx.y * 32;
  const int l0 = blockIdx.x * 32;
  const int tx = threadIdx.x & 31, ty = threadIdx.x >> 5;  // ty in 0..7
  const float* xb = x + ((size_t)b * CIN + c0) * LLEN + l0;
#pragma unroll
  for (int i = 0; i < 4; ++i)
    tile[ty + 8 * i][tx] = xb[(size_t)(ty + 8 * i) * LLEN + tx];
  __syncthreads();
  unsigned short* dst = xtp + ((size_t)b * LPAD + 8 + l0) * CIN + c0;
#pragma unroll
  for (int i = 0; i < 4; ++i) {
    int li = ty + 8 * i;
    dst[(size_t)li * CIN + tx] = f2bf(tile[tx][li]);
  }
}

// ---------------- fused conv GEMM ----------------
// C[o][l] (128x128 tile) = sum over k (8 taps) and c (CIN) of
//   W[k*COUT+o][c] * xT[l-k][c]   ; bias added in epilogue.
// A = Wb rows (K-contiguous), B = xtp rows (K-contiguous). B staged once per
// c-tile with an 8-row halo and reused across all 8 taps (row shift = tap shift).

__global__ __launch_bounds__(256) void conv_gemm_kernel(
    const unsigned short* __restrict__ Wb,   // (K*COUT, CIN) bf16
    const unsigned short* __restrict__ xtp,  // (B, LPAD, CIN) bf16
    const float* __restrict__ bias,          // (COUT)
    float* __restrict__ y)                   // (B, COUT, LLEN) fp32
{
  __shared__ __align__(16) unsigned short As[128 * 32];  // 8 KB
  __shared__ __align__(16) unsigned short Bs[136 * 32];  // 8.5 KB (halo)

  const int t    = threadIdx.x;
  const int lane = t & 63;
  const int wid  = t >> 6;
  const int wm   = wid & 1, wn = wid >> 1;
  const int l0   = blockIdx.x * 128;
  const int o0   = blockIdx.y * 128;
  const int b    = blockIdx.z;

  const int quad = lane >> 4;
  const int lrow = lane & 15;

  f32x4_t acc[4][4];
#pragma unroll
  for (int i = 0; i < 4; ++i)
#pragma unroll
    for (int j = 0; j < 4; ++j)
      acc[i][j] = (f32x4_t){0.f, 0.f, 0.f, 0.f};

  // staging coords: each thread moves one 16B chunk (8 bf16) per round.
  // LDS write side is forced lane-contiguous (global_load_lds), so we swizzle
  // the SOURCE chunk within the 64B row: slot s holds global chunk s ^ ((row>>1)&3).
  const int srow   = t >> 2;                          // 0..63 per round
  const int schunk = (t & 3) ^ ((srow >> 1) & 3);     // swizzled source chunk
  const int lds_off = t * 8;                          // elements (t*16 bytes)

  const unsigned short* xb = xtp + (size_t)b * LPAD * CIN;

#pragma unroll 1
  for (int ct = 0; ct < 16; ++ct) {
    const int c0 = ct * 32;
    // stage B halo: LDS rows r=0..135  <-  xtp rows (l0 + r)  [l = l0 - 8 + r]
    {
      const unsigned short* src = xb + (size_t)(l0 + srow) * CIN + c0 + schunk * 8;
      gl2lds16(Bs + lds_off, src);
      gl2lds16(Bs + 64 * 32 + lds_off, src + 64 * CIN);
      if (t < 32)
        gl2lds16(Bs + 128 * 32 + lds_off, src + 128 * CIN);
    }
#pragma unroll
    for (int k = 0; k < 8; ++k) {
      // stage A: W rows k*COUT + o0 + (0..127), cols c0..c0+31
      const unsigned short* asrc =
          Wb + (size_t)(k * COUT + o0 + srow) * CIN + c0 + schunk * 8;
      gl2lds16(As + lds_off, asrc);
      gl2lds16(As + 64 * 32 + lds_off, asrc + 64 * CIN);
      __syncthreads();  // compiler drains vmcnt before s_barrier -> staging done

      bf16x8_t af[4], bfr[4];
#pragma unroll
      for (int i = 0; i < 4; ++i) {
        int row = wm * 64 + i * 16 + lrow;
        int off = row * 32 + ((quad ^ ((row >> 1) & 3)) * 8);
        af[i] = *(const bf16x8_t*)(As + off);
      }
#pragma unroll
      for (int j = 0; j < 4; ++j) {
        int row = (8 - k) + wn * 64 + j * 16 + lrow;   // halo shift: l = l0+n-k
        int off = row * 32 + ((quad ^ ((row >> 1) & 3)) * 8);
        bfr[j] = *(const bf16x8_t*)(Bs + off);
      }
#pragma unroll
      for (int i = 0; i < 4; ++i)
#pragma unroll
        for (int j = 0; j < 4; ++j)
          acc[i][j] = __builtin_amdgcn_mfma_f32_16x16x32_bf16(af[i], bfr[j], acc[i][j], 0, 0, 0);
      __syncthreads();  // all waves done reading before next tap's A staging
    }
  }

  // epilogue: D layout col = lane&15 (=l), row = quad*4+reg (=o)
#pragma unroll
  for (int i = 0; i < 4; ++i) {
    const int o_base = o0 + wm * 64 + i * 16 + quad * 4;
    const float4 bv = *(const float4*)(bias + o_base);
    const float bvr[4] = {bv.x, bv.y, bv.z, bv.w};
#pragma unroll
    for (int j = 0; j < 4; ++j) {
      const int l = l0 + wn * 64 + j * 16 + lrow;
#pragma unroll
      for (int r = 0; r < 4; ++r) {
        y[((size_t)b * COUT + o_base + r) * LLEN + l] = acc[i][j][r] + bvr[r];
      }
    }
  }
}

// ---------------- launch ----------------

extern "C" void kernel_launch(void* const* d_in, const int* in_sizes, int n_in,
                              void* d_out, int out_size, void* d_ws, size_t ws_size,
                              hipStream_t stream) {
  const float* x    = (const float*)d_in[0];   // (8, 512, 2048)
  const float* W    = (const float*)d_in[1];   // (4096, 512)
  const float* bias = (const float*)d_in[2];   // (512)
  float* y          = (float*)d_out;           // (8, 512, 2048)

  unsigned short* xtp = (unsigned short*)d_ws;                     // 16,842,752 B
  unsigned short* Wb  = (unsigned short*)((char*)d_ws +
                        (size_t)BATCH * LPAD * CIN * sizeof(unsigned short));
  // total ws use: ~20.1 MB

  zero_pad_kernel<<<BATCH, 256, 0, stream>>>(xtp);
  convert_w_kernel<<<(KTAP * COUT * CIN / 4) / 256, 256, 0, stream>>>(
      (const float4*)W, (ushort4*)Wb);
  transpose_x_kernel<<<dim3(LLEN / 32, CIN / 32, BATCH), 256, 0, stream>>>(x, xtp);
  conv_gemm_kernel<<<dim3(LLEN / 128, COUT / 128, BATCH), 256, 0, stream>>>(
      Wb, xtp, bias, y);
}

// Round 2
// 150.026 us; speedup vs baseline: 1.0760x; 1.0760x over previous
//
#include <hip/hip_runtime.h>
#include <hip/hip_bf16.h>
#include <cstdint>
#include <cstddef>

#define CIN   512
#define COUT  512
#define LLEN  2048
#define BATCH 8
#define KTAP  8
#define LPAD  (LLEN + 8)   // 8 zero halo rows at the front of each batch

typedef __bf16 bf16x8_t __attribute__((ext_vector_type(8)));
typedef float  f32x4_t  __attribute__((ext_vector_type(4)));
typedef unsigned short u16x8_t __attribute__((ext_vector_type(8)));

__device__ __forceinline__ unsigned short f2bf(float f) {
  __bf16 h = (__bf16)f;                       // RNE fptrunc
  return __builtin_bit_cast(unsigned short, h);
}

__device__ __forceinline__ void gl2lds16(unsigned short* lds, const unsigned short* g) {
  __builtin_amdgcn_global_load_lds(
      (const __attribute__((address_space(1))) unsigned int*)g,
      (__attribute__((address_space(3))) unsigned int*)lds,
      16, 0, 0);
}

// ---------------- pre-pass kernels ----------------

// W (COUT*K, CIN) fp32 -> bf16, same layout. 8 elements/thread.
__global__ void convert_w_kernel(const float4* __restrict__ W, u16x8_t* __restrict__ Wb) {
  int idx = blockIdx.x * 256 + threadIdx.x;   // grid: (4096*512/8)/256 = 1024 blocks
  float4 a = W[idx * 2], b = W[idx * 2 + 1];
  u16x8_t o;
  o[0] = f2bf(a.x); o[1] = f2bf(a.y); o[2] = f2bf(a.z); o[3] = f2bf(a.w);
  o[4] = f2bf(b.x); o[5] = f2bf(b.y); o[6] = f2bf(b.z); o[7] = f2bf(b.w);
  Wb[idx] = o;
}

// x (B, CIN, L) fp32 -> xtp (B, 8+L, CIN) bf16 (transpose + cast).
// 64(c) x 64(l) tiles; float4 loads, LDS (pad 65) transpose, ushort8 stores.
// Blocks at l0==0 also zero the 8-row halo for their c-range.
__global__ __launch_bounds__(256) void transpose_x_kernel(
    const float* __restrict__ x, unsigned short* __restrict__ xtp) {
  __shared__ float tile[64][65];
  const int t  = threadIdx.x;
  const int b  = blockIdx.z;
  const int c0 = blockIdx.y * 64;
  const int l0 = blockIdx.x * 64;

  // halo zeroing (first l-tile only): rows 0..7, cols c0..c0+63
  if (blockIdx.x == 0 && t < 64) {
    unsigned short* hp = xtp + ((size_t)b * LPAD + (t >> 3)) * CIN + c0 + (t & 7) * 8;
    *(u16x8_t*)hp = (u16x8_t){0, 0, 0, 0, 0, 0, 0, 0};
  }

  // load: 64 c-rows x 64 l, 4 threads/row, 4 float4 each (16 contiguous l)
  {
    const int cr = t >> 2;              // 0..63
    const int lv = (t & 3) * 16;        // 0,16,32,48
    const float* src = x + ((size_t)b * CIN + c0 + cr) * LLEN + l0 + lv;
#pragma unroll
    for (int i = 0; i < 4; ++i) {
      float4 v = *(const float4*)(src + 4 * i);
      tile[cr][lv + 4 * i + 0] = v.x;
      tile[cr][lv + 4 * i + 1] = v.y;
      tile[cr][lv + 4 * i + 2] = v.z;
      tile[cr][lv + 4 * i + 3] = v.w;
    }
  }
  __syncthreads();

  // store transposed: 64 l-rows, 4 threads/row, 16 c each (2x ushort8)
  {
    const int l    = t >> 2;            // 0..63
    const int cseg = (t & 3) * 16;      // 0,16,32,48
    unsigned short ov[16];
#pragma unroll
    for (int u = 0; u < 16; ++u) ov[u] = f2bf(tile[cseg + u][l]);
    unsigned short* dst = xtp + ((size_t)b * LPAD + 8 + l0 + l) * CIN + c0 + cseg;
    *(u16x8_t*)dst       = *(const u16x8_t*)&ov[0];
    *(u16x8_t*)(dst + 8) = *(const u16x8_t*)&ov[8];
  }
}

// ---------------- fused conv GEMM (BK=64) ----------------
// C[o][l] (128x128 tile) = sum over k (8 taps) and c (CIN) of
//   W[k*COUT+o][c] * xT[l-k][c]   ; bias added in epilogue.
// B staged once per 64-deep c-tile with an 8-row halo, reused across all 8
// taps (row shift = tap shift). A staged per tap. 32 MFMA per barrier pair.

__global__ __launch_bounds__(256) void conv_gemm_kernel(
    const unsigned short* __restrict__ Wb,   // (K*COUT, CIN) bf16
    const unsigned short* __restrict__ xtp,  // (B, LPAD, CIN) bf16
    const float* __restrict__ bias,          // (COUT)
    float* __restrict__ y)                   // (B, COUT, LLEN) fp32
{
  __shared__ __align__(16) unsigned short As[128 * 64];  // 16 KB
  __shared__ __align__(16) unsigned short Bs[136 * 64];  // 17 KB (halo)

  const int t    = threadIdx.x;
  const int lane = t & 63;
  const int wid  = t >> 6;
  const int wm   = wid & 1, wn = wid >> 1;
  const int l0   = blockIdx.x * 128;
  const int o0   = blockIdx.y * 128;
  const int b    = blockIdx.z;

  const int quad = lane >> 4;
  const int lrow = lane & 15;

  f32x4_t acc[4][4];
#pragma unroll
  for (int i = 0; i < 4; ++i)
#pragma unroll
    for (int j = 0; j < 4; ++j)
      acc[i][j] = (f32x4_t){0.f, 0.f, 0.f, 0.f};

  // staging: rows of 64 bf16 = 128 B = 8 chunks of 16 B. LDS slot s of row r
  // holds source chunk s ^ (r & 7) (write side is lane-contiguous, so the
  // swizzle is applied on the SOURCE address).
  const int srow    = t >> 3;                       // 0..31 per round
  const int schunk  = (t & 7) ^ (srow & 7);         // swizzled source chunk
  const int lds_off = t * 8;                        // elements (t*16 bytes)

  const unsigned short* xb = xtp + (size_t)b * LPAD * CIN;

#pragma unroll 1
  for (int ct = 0; ct < 8; ++ct) {
    const int c0 = ct * 64;
    // stage B halo: LDS rows r=0..135 <- xtp rows (l0 + r)  [l = l0 - 8 + r]
    {
      const unsigned short* src = xb + (size_t)(l0 + srow) * CIN + c0 + schunk * 8;
#pragma unroll
      for (int rd = 0; rd < 4; ++rd)
        gl2lds16(Bs + lds_off + rd * 2048, src + (size_t)rd * 32 * CIN);
      if (t < 64) {
        const int r2 = 128 + (t >> 3);
        const int ch2 = (t & 7) ^ (r2 & 7);
        gl2lds16(Bs + 128 * 64 + t * 8,
                 xb + (size_t)(l0 + r2) * CIN + c0 + ch2 * 8);
      }
    }
#pragma unroll
    for (int k = 0; k < 8; ++k) {
      // stage A: W rows k*COUT + o0 + (0..127), cols c0..c0+63
      const unsigned short* asrc =
          Wb + (size_t)(k * COUT + o0 + srow) * CIN + c0 + schunk * 8;
#pragma unroll
      for (int rd = 0; rd < 4; ++rd)
        gl2lds16(As + lds_off + rd * 2048, asrc + (size_t)rd * 32 * CIN);
      __syncthreads();  // drains vmcnt before s_barrier -> staging complete

#pragma unroll
      for (int h = 0; h < 2; ++h) {
        bf16x8_t af[4], bfr[4];
#pragma unroll
        for (int i = 0; i < 4; ++i) {
          int row  = wm * 64 + i * 16 + lrow;
          int slot = (h * 4 + quad) ^ (row & 7);
          af[i] = *(const bf16x8_t*)(As + row * 64 + slot * 8);
        }
#pragma unroll
        for (int j = 0; j < 4; ++j) {
          int row  = (8 - k) + wn * 64 + j * 16 + lrow;   // halo shift
          int slot = (h * 4 + quad) ^ (row & 7);
          bfr[j] = *(const bf16x8_t*)(Bs + row * 64 + slot * 8);
        }
#pragma unroll
        for (int i = 0; i < 4; ++i)
#pragma unroll
          for (int j = 0; j < 4; ++j)
            acc[i][j] = __builtin_amdgcn_mfma_f32_16x16x32_bf16(af[i], bfr[j], acc[i][j], 0, 0, 0);
      }
      __syncthreads();  // all waves done reading before next tap's A staging
    }
  }

  // epilogue: D layout col = lane&15 (=l), row = quad*4+reg (=o)
#pragma unroll
  for (int i = 0; i < 4; ++i) {
    const int o_base = o0 + wm * 64 + i * 16 + quad * 4;
    const float4 bv = *(const float4*)(bias + o_base);
    const float bvr[4] = {bv.x, bv.y, bv.z, bv.w};
#pragma unroll
    for (int j = 0; j < 4; ++j) {
      const int l = l0 + wn * 64 + j * 16 + lrow;
#pragma unroll
      for (int r = 0; r < 4; ++r) {
        y[((size_t)b * COUT + o_base + r) * LLEN + l] = acc[i][j][r] + bvr[r];
      }
    }
  }
}

// ---------------- launch ----------------

extern "C" void kernel_launch(void* const* d_in, const int* in_sizes, int n_in,
                              void* d_out, int out_size, void* d_ws, size_t ws_size,
                              hipStream_t stream) {
  const float* x    = (const float*)d_in[0];   // (8, 512, 2048)
  const float* W    = (const float*)d_in[1];   // (4096, 512)
  const float* bias = (const float*)d_in[2];   // (512)
  float* y          = (float*)d_out;           // (8, 512, 2048)

  unsigned short* xtp = (unsigned short*)d_ws;                     // 16,842,752 B
  unsigned short* Wb  = (unsigned short*)((char*)d_ws +
                        (size_t)BATCH * LPAD * CIN * sizeof(unsigned short));

  convert_w_kernel<<<(KTAP * COUT * CIN / 8) / 256, 256, 0, stream>>>(
      (const float4*)W, (u16x8_t*)Wb);
  transpose_x_kernel<<<dim3(LLEN / 64, CIN / 64, BATCH), 256, 0, stream>>>(x, xtp);
  conv_gemm_kernel<<<dim3(LLEN / 128, COUT / 128, BATCH), 256, 0, stream>>>(
      Wb, xtp, bias, y);
}